// Round 1
// baseline (5257.868 us; speedup 1.0000x reference)
//
#include <hip/hip_runtime.h>

typedef unsigned short u16;
typedef unsigned int u32;
typedef __attribute__((ext_vector_type(8))) short bf16x8;
typedef __attribute__((ext_vector_type(4))) float f32x4;

#define MFMA_BF16(a,b,c) __builtin_amdgcn_mfma_f32_16x16x32_bf16((a),(b),(c),0,0,0)

__device__ __forceinline__ u16 f2bf(float f) {
  union { float f; u32 u; } v; v.f = f;
  u32 r = v.u + 0x7FFFu + ((v.u >> 16) & 1u);
  return (u16)(r >> 16);
}
__device__ __forceinline__ float tanh_fast(float x) {
  float e = __expf(2.0f * x);
  return 1.0f - 2.0f / (e + 1.0f);
}

// ---------------------------------------------------------------------------
// Prep: bf16 conversions, weight concatenation, embedding gather, state init
// ---------------------------------------------------------------------------
__global__ void prep_kernel(
    const float* __restrict__ fcw, const float* __restrict__ enc,
    const float* __restrict__ wenc, const float* __restrict__ wdec,
    const float* __restrict__ wih0, const float* __restrict__ whh0,
    const float* __restrict__ wih1, const float* __restrict__ whh1,
    const float* __restrict__ bih0, const float* __restrict__ bhh0,
    const float* __restrict__ bih1, const float* __restrict__ bhh1,
    const float* __restrict__ emb, const int* __restrict__ yin,
    const float* __restrict__ dih,
    u16* __restrict__ fcwb, u16* __restrict__ encb, u16* __restrict__ wencb,
    u16* __restrict__ wdecb, u16* __restrict__ w0cat, u16* __restrict__ w1cat,
    u16* __restrict__ embbt, float* __restrict__ bias0, float* __restrict__ bias1,
    u16* __restrict__ x0_0, u16* __restrict__ x1_0)
{
  const long long total = 43845632LL;
  for (long long i = (long long)blockIdx.x * 256 + threadIdx.x; i < total;
       i += (long long)gridDim.x * 256) {
    if (i < 32768000LL) {                    // fc_w bf16, padded to 32000 rows
      int r = (int)(i >> 10), c = (int)(i & 1023);
      fcwb[i] = (r < 31999) ? f2bf(fcw[(long long)r * 1024 + c]) : (u16)0;
    } else if (i < 36962304LL) {             // encoder_outputs bf16
      long long j = i - 32768000LL; encb[j] = f2bf(enc[j]);
    } else if (i < 37486592LL) {             // W_enc bf16
      long long j = i - 36962304LL; wencb[j] = f2bf(wenc[j]);
    } else if (i < 38010880LL) {             // W_dec bf16
      long long j = i - 37486592LL; wdecb[j] = f2bf(wdec[j]);
    } else if (i < 40632320LL) {             // W0cat = [W_ih0 | W_hh0]  [1024][2560]
      long long j = i - 38010880LL;
      int r = (int)(j / 2560), c = (int)(j % 2560);
      w0cat[j] = f2bf(c < 1536 ? wih0[(long long)r * 1536 + c]
                               : whh0[(long long)r * 1024 + (c - 1536)]);
    } else if (i < 42729472LL) {             // W1cat = [W_ih1 | W_hh1]  [1024][2048]
      long long j = i - 40632320LL;
      int r = (int)(j >> 11), c = (int)(j & 2047);
      w1cat[j] = f2bf(c < 1024 ? wih1[(r << 10) + c] : whh1[(r << 10) + (c - 1024)]);
    } else if (i < 43778048LL) {             // embedding gather -> bf16 [2048][512]
      long long j = i - 42729472LL;
      int bt = (int)(j >> 9), c = (int)(j & 511);
      int y = yin[bt];
      embbt[j] = f2bf(emb[(long long)y * 512 + c]);
    } else if (i < 43779072LL) {             // bias0 = b_ih0 + b_hh0
      int j = (int)(i - 43778048LL); bias0[j] = bih0[j] + bhh0[j];
    } else if (i < 43780096LL) {             // bias1
      int j = (int)(i - 43779072LL); bias1[j] = bih1[j] + bhh1[j];
    } else if (i < 43812864LL) {             // h0 init -> x0[0][:,1536:]
      int j = (int)(i - 43780096LL); int b = j >> 10, c = j & 1023;
      x0_0[b * 2560 + 1536 + c] = f2bf(dih[j]);
    } else {                                 // h1 init -> x1[0][:,1024:]
      int j = (int)(i - 43812864LL); int b = j >> 10, c = j & 1023;
      x1_0[b * 2048 + 1024 + c] = f2bf(dih[32768 + j]);
    }
  }
}

// ---------------------------------------------------------------------------
// Generic 128x128-tile bf16 MFMA GEMM:  C[M][N] = A[M][K] * B[N][K]^T + bias
// A,B bf16 row-major (ld=K). C f32 (ld=ldc), stores only col < Nvalid.
// grid.x = (M/128)*ntN, block = 256 (4 waves, 2x2 of 64x64)
// ---------------------------------------------------------------------------
__global__ __launch_bounds__(256) void gemm128(
    const u16* __restrict__ A, const u16* __restrict__ Bm,
    const float* __restrict__ bias, float* __restrict__ C,
    int K, int ldc, int Nvalid, int ntN)
{
  __shared__ u16 As[128 * 32];
  __shared__ u16 Bs[128 * 32];
  const int tid = threadIdx.x;
  const int bid = blockIdx.x;
  const int tM = bid / ntN, tN = bid - tM * ntN;
  const int m0 = tM * 128, n0 = tN * 128;
  const int lane = tid & 63, wid = tid >> 6;
  const int wm = wid >> 1, wn = wid & 1;
  const int srow = tid >> 1, scol = (tid & 1) * 16;

  const u16* gA = A + (size_t)(m0 + srow) * K + scol;
  const u16* gB = Bm + (size_t)(n0 + srow) * K + scol;
  u16* sA = &As[srow * 32 + scol];
  u16* sB = &Bs[srow * 32 + scol];

  f32x4 acc[4][4];
#pragma unroll
  for (int i = 0; i < 4; ++i)
#pragma unroll
    for (int j = 0; j < 4; ++j) acc[i][j] = (f32x4){0, 0, 0, 0};

  const int aoff = (wm * 64 + (lane & 15)) * 32 + ((lane >> 4) << 3);
  const int boff = (wn * 64 + (lane & 15)) * 32 + ((lane >> 4) << 3);

  for (int k0 = 0; k0 < K; k0 += 32) {
    bf16x8 va0 = *(const bf16x8*)(gA + k0);
    bf16x8 va1 = *(const bf16x8*)(gA + k0 + 8);
    bf16x8 vb0 = *(const bf16x8*)(gB + k0);
    bf16x8 vb1 = *(const bf16x8*)(gB + k0 + 8);
    __syncthreads();
    *((bf16x8*)sA) = va0;  *((bf16x8*)(sA + 8)) = va1;
    *((bf16x8*)sB) = vb0;  *((bf16x8*)(sB + 8)) = vb1;
    __syncthreads();
    bf16x8 af[4], bfj[4];
#pragma unroll
    for (int i = 0; i < 4; ++i) af[i] = *(const bf16x8*)&As[aoff + i * 512];
#pragma unroll
    for (int j = 0; j < 4; ++j) bfj[j] = *(const bf16x8*)&Bs[boff + j * 512];
#pragma unroll
    for (int i = 0; i < 4; ++i)
#pragma unroll
      for (int j = 0; j < 4; ++j)
        acc[i][j] = MFMA_BF16(af[i], bfj[j], acc[i][j]);
  }

#pragma unroll
  for (int i = 0; i < 4; ++i) {
#pragma unroll
    for (int j = 0; j < 4; ++j) {
      int row = m0 + wm * 64 + i * 16 + ((lane >> 4) << 2);
      int cc = n0 + wn * 64 + j * 16 + (lane & 15);
      if (cc < Nvalid) {
        float bs = bias ? bias[cc] : 0.f;
#pragma unroll
        for (int jj = 0; jj < 4; ++jj)
          C[(size_t)(row + jj) * ldc + cc] = acc[i][j][jj] + bs;
      }
    }
  }
}

// ---------------------------------------------------------------------------
// Skinny recurrent GEMM: out[32][N] = X[32][KD] * W[N][KD]^T  (+bias, tanh)
// MODE 0: tanh(acc+bias) -> bf16 to two destinations
// MODE 1: raw f32 -> fout (ld=ldo)
// grid.x = N/32, block = 256 (4 waves, each one 16x16 fragment)
// ---------------------------------------------------------------------------
template <int KD, int MODE>
__global__ __launch_bounds__(256) void rnn_gemm(
    const u16* __restrict__ X, int ldx,
    const u16* __restrict__ W,
    const float* __restrict__ bias,
    u16* __restrict__ d1, int ld1, int o1,
    u16* __restrict__ d2, int ld2, int o2,
    float* __restrict__ fout, int ldo)
{
  const int tid = threadIdx.x;
  const int lane = tid & 63, wid = tid >> 6;
  const int mh = wid & 1, nq = wid >> 1;
  const int n0 = blockIdx.x * 32 + nq * 16;
  const int lrow = lane & 15;
  const int lk = (lane >> 4) << 3;
  const u16* xa = X + (size_t)(mh * 16 + lrow) * ldx + lk;
  const u16* wb = W + (size_t)(n0 + lrow) * KD + lk;

  f32x4 acc = {0, 0, 0, 0};
  constexpr int G = KD / 256;
#pragma unroll
  for (int g = 0; g < G; ++g) {
    bf16x8 a[8], bb[8];
#pragma unroll
    for (int u = 0; u < 8; ++u) {
      a[u]  = *(const bf16x8*)(xa + g * 256 + u * 32);
      bb[u] = *(const bf16x8*)(wb + g * 256 + u * 32);
    }
#pragma unroll
    for (int u = 0; u < 8; ++u) acc = MFMA_BF16(a[u], bb[u], acc);
  }

  const int col = n0 + lrow;
  const int rbase = mh * 16 + ((lane >> 4) << 2);
  if (MODE == 0) {
    float bs = bias[col];
#pragma unroll
    for (int j = 0; j < 4; ++j) {
      int row = rbase + j;
      u16 hv = f2bf(tanh_fast(acc[j] + bs));
      d1[(size_t)row * ld1 + o1 + col] = hv;
      d2[(size_t)row * ld2 + o2 + col] = hv;
    }
  } else {
#pragma unroll
    for (int j = 0; j < 4; ++j) fout[(size_t)(rbase + j) * ldo + col] = acc[j];
  }
}

// ---------------------------------------------------------------------------
// Per-step attention: scores=tanh(enc_proj+dec_p)@v_w, mask, softmax,
// context = attn@enc_out; writes emb_t and context into x0[t&1]; attn -> out.
// grid = 32 (one block per batch b), block = 256
// ---------------------------------------------------------------------------
__global__ __launch_bounds__(256) void attn_step(
    const float* __restrict__ decp,     // [32][512]
    const float* __restrict__ encproj,  // [32*128][512]
    const float* __restrict__ enc,      // [32][128][1024] f32
    const int* __restrict__ mask,       // [32][128]
    const float* __restrict__ vw,       // [512]
    const u16* __restrict__ embbt,      // [2048][512]
    u16* __restrict__ x0w,              // x0[t&1]  [32][2560]
    float* __restrict__ attn_out,       // d_out attn region
    int t)
{
  __shared__ float dp[512];
  __shared__ float vws[512];
  __shared__ float sc[128];
  __shared__ float red[4];
  const int tid = threadIdx.x;
  const int b = blockIdx.x;

  for (int i = tid; i < 512; i += 256) { dp[i] = decp[b * 512 + i]; vws[i] = vw[i]; }
  u16* x0row = x0w + b * 2560;
  ((u32*)x0row)[tid] = ((const u32*)(embbt + (size_t)(b * 64 + t) * 512))[tid];
  __syncthreads();

  {
    const int s = tid >> 1, h = tid & 1;
    const float* ep = encproj + (size_t)(b * 128 + s) * 512 + h * 256;
    const float* dph = dp + h * 256;
    const float* vwh = vws + h * 256;
    float a = 0.f;
#pragma unroll 4
    for (int i = 0; i < 256; ++i) a += vwh[i] * tanh_fast(ep[i] + dph[i]);
    a += __shfl_xor(a, 1);
    if (h == 0) sc[s] = (mask[b * 128 + s] == 0) ? -1e9f : a;
  }
  __syncthreads();

  float v = (tid < 128) ? sc[tid] : -1e30f;
  float m = v;
#pragma unroll
  for (int off = 32; off >= 1; off >>= 1) m = fmaxf(m, __shfl_xor(m, off));
  if ((tid & 63) == 0) red[tid >> 6] = m;
  __syncthreads();
  m = fmaxf(fmaxf(red[0], red[1]), fmaxf(red[2], red[3]));
  float e = (tid < 128) ? __expf(v - m) : 0.f;
  float ssum = e;
#pragma unroll
  for (int off = 32; off >= 1; off >>= 1) ssum += __shfl_xor(ssum, off);
  __syncthreads();
  if ((tid & 63) == 0) red[tid >> 6] = ssum;
  __syncthreads();
  float tot = red[0] + red[1] + red[2] + red[3];
  float at = e / tot;
  if (tid < 128) { sc[tid] = at; attn_out[(size_t)(b * 64 + t) * 128 + tid] = at; }
  __syncthreads();

  float4 cacc = {0, 0, 0, 0};
  const float4* erow = (const float4*)(enc + (size_t)b * 131072) + tid;
#pragma unroll 4
  for (int s = 0; s < 128; ++s) {
    float w = sc[s];
    float4 ev = erow[s * 256];
    cacc.x += w * ev.x; cacc.y += w * ev.y; cacc.z += w * ev.z; cacc.w += w * ev.w;
  }
  u16* cdst = x0row + 512 + tid * 4;
  cdst[0] = f2bf(cacc.x); cdst[1] = f2bf(cacc.y);
  cdst[2] = f2bf(cacc.z); cdst[3] = f2bf(cacc.w);
}

// ---------------------------------------------------------------------------
extern "C" void kernel_launch(void* const* d_in, const int* in_sizes, int n_in,
                              void* d_out, int out_size, void* d_ws, size_t ws_size,
                              hipStream_t stream)
{
  const int*   yin  = (const int*)d_in[0];
  const float* enc  = (const float*)d_in[1];
  const float* dih  = (const float*)d_in[2];
  const int*   msk  = (const int*)d_in[3];
  const float* emb  = (const float*)d_in[4];
  const float* wenc = (const float*)d_in[5];
  const float* wdec = (const float*)d_in[6];
  const float* vw   = (const float*)d_in[7];
  const float* wih0 = (const float*)d_in[8];
  const float* whh0 = (const float*)d_in[9];
  const float* bih0 = (const float*)d_in[10];
  const float* bhh0 = (const float*)d_in[11];
  const float* wih1 = (const float*)d_in[12];
  const float* whh1 = (const float*)d_in[13];
  const float* bih1 = (const float*)d_in[14];
  const float* bhh1 = (const float*)d_in[15];
  const float* fcw  = (const float*)d_in[16];
  const float* fcb  = (const float*)d_in[17];

  char* ws = (char*)d_ws;
  size_t off = 0;
  auto alloc = [&](size_t bytes) {
    char* p = ws + off; off += (bytes + 255) & ~(size_t)255; return p;
  };
  u16*   fcwb    = (u16*)alloc(32000ULL * 1024 * 2);
  u16*   encb    = (u16*)alloc(4194304ULL * 2);
  u16*   wencb   = (u16*)alloc(524288ULL * 2);
  u16*   wdecb   = (u16*)alloc(524288ULL * 2);
  u16*   w0cat   = (u16*)alloc(2621440ULL * 2);
  u16*   w1cat   = (u16*)alloc(2097152ULL * 2);
  u16*   embbt   = (u16*)alloc(1048576ULL * 2);
  float* encproj = (float*)alloc(2097152ULL * 4);
  float* decp    = (float*)alloc(16384ULL * 4);
  float* bias0   = (float*)alloc(1024ULL * 4);
  float* bias1   = (float*)alloc(1024ULL * 4);
  u16*   x0buf   = (u16*)alloc(2ULL * 32 * 2560 * 2);
  u16*   x1buf   = (u16*)alloc(2ULL * 32 * 2048 * 2);
  u16*   h1all   = (u16*)alloc(2097152ULL * 2);
  if (off > ws_size) return;  // workspace too small -> visible failure

  float* outlog  = (float*)d_out;                 // [2048][31999]
  float* outattn = outlog + 65533952ULL;          // [32][64][128]

  prep_kernel<<<2048, 256, 0, stream>>>(
      fcw, enc, wenc, wdec, wih0, whh0, wih1, whh1,
      bih0, bhh0, bih1, bhh1, emb, yin, dih,
      fcwb, encb, wencb, wdecb, w0cat, w1cat, embbt, bias0, bias1,
      x0buf, x1buf);

  // enc_proj: [4096][512] = encb[4096][1024] @ wencb[512][1024]^T
  gemm128<<<32 * 4, 256, 0, stream>>>(encb, wencb, nullptr, encproj,
                                      1024, 512, 512, 4);

  for (int t = 0; t < 64; ++t) {
    u16* x0r  = x0buf + (size_t)(t & 1) * 32 * 2560;
    u16* x0w2 = x0buf + (size_t)((t + 1) & 1) * 32 * 2560;
    u16* x1r  = x1buf + (size_t)(t & 1) * 32 * 2048;
    u16* x1w2 = x1buf + (size_t)((t + 1) & 1) * 32 * 2048;

    // dec_p[32][512] = h1_prev @ W_dec^T
    rnn_gemm<1024, 1><<<16, 256, 0, stream>>>(
        x1r + 1024, 2048, wdecb, nullptr,
        nullptr, 0, 0, nullptr, 0, 0, decp, 512);

    // attention + softmax + context; fills x0[t&1][:,0:1536]
    attn_step<<<32, 256, 0, stream>>>(decp, encproj, enc, msk, vw, embbt,
                                      x0r, outattn, t);

    // h0 = tanh(x0 @ W0cat^T + bias0) -> x1[t&1][:, :1024] and x0[(t+1)&1][:,1536:]
    rnn_gemm<2560, 0><<<32, 256, 0, stream>>>(
        x0r, 2560, w0cat, bias0,
        x1r, 2048, 0, x0w2, 2560, 1536, nullptr, 0);

    // h1 = tanh(x1 @ W1cat^T + bias1) -> x1[(t+1)&1][:,1024:] and H1_all[b*64+t]
    rnn_gemm<2048, 0><<<32, 256, 0, stream>>>(
        x1r, 2048, w1cat, bias1,
        x1w2, 2048, 1024, h1all + (size_t)t * 1024, 64 * 1024, 0, nullptr, 0);
  }

  // logits: [2048][31999] = H1_all[2048][1024] @ fcwb[32000][1024]^T + fc_b
  gemm128<<<16 * 250, 256, 0, stream>>>(h1all, fcwb, fcb, outlog,
                                        1024, 31999, 31999, 250);
}

// Round 2
// 3472.961 us; speedup vs baseline: 1.5139x; 1.5139x over previous
//
#include <hip/hip_runtime.h>

typedef unsigned short u16;
typedef unsigned int u32;
typedef __attribute__((ext_vector_type(8))) short bf16x8;
typedef __attribute__((ext_vector_type(4))) float f32x4;

#define MFMA_BF16(a,b,c) __builtin_amdgcn_mfma_f32_16x16x32_bf16((a),(b),(c),0,0,0)

#define X0SZ 81920   // 32*2560 u16 per buffer
#define X1SZ 65536   // 32*2048 u16 per buffer

__device__ __forceinline__ u16 f2bf(float f) {
  union { float f; u32 u; } v; v.f = f;
  u32 r = v.u + 0x7FFFu + ((v.u >> 16) & 1u);
  return (u16)(r >> 16);
}
__device__ __forceinline__ float bf2f(u16 h) {
  union { u32 u; float f; } v; v.u = ((u32)h) << 16; return v.f;
}
__device__ __forceinline__ float tanh_fast(float x) {
  float e = __expf(2.0f * x);
  return 1.0f - 2.0f / (e + 1.0f);
}

// ---- inter-block handoff primitives (device-scope) -------------------------
__device__ __forceinline__ void wait_ge(u32* c, u32 target) {
  if (threadIdx.x == 0) {
    while (__hip_atomic_load(c, __ATOMIC_RELAXED, __HIP_MEMORY_SCOPE_AGENT) < target)
      __builtin_amdgcn_s_sleep(2);
    __builtin_amdgcn_fence(__ATOMIC_ACQUIRE, "agent");
  }
  __syncthreads();
}
__device__ __forceinline__ void post_add(u32* c) {
  __syncthreads();
  if (threadIdx.x == 0) {
    __builtin_amdgcn_fence(__ATOMIC_RELEASE, "agent");
    __hip_atomic_fetch_add(c, 1u, __ATOMIC_RELAXED, __HIP_MEMORY_SCOPE_AGENT);
  }
}

// ---------------------------------------------------------------------------
// Prep: bf16 conversions, weight concatenation, embedding gather, state init
// ---------------------------------------------------------------------------
__global__ void prep_kernel(
    const float* __restrict__ fcw, const float* __restrict__ enc,
    const float* __restrict__ wenc, const float* __restrict__ wdec,
    const float* __restrict__ wih0, const float* __restrict__ whh0,
    const float* __restrict__ wih1, const float* __restrict__ whh1,
    const float* __restrict__ bih0, const float* __restrict__ bhh0,
    const float* __restrict__ bih1, const float* __restrict__ bhh1,
    const float* __restrict__ emb, const int* __restrict__ yin,
    const float* __restrict__ dih,
    u16* __restrict__ fcwb, u16* __restrict__ encb, u16* __restrict__ wencb,
    u16* __restrict__ wdecb, u16* __restrict__ w0cat, u16* __restrict__ w1cat,
    u16* __restrict__ embbt, float* __restrict__ bias0, float* __restrict__ bias1,
    u16* __restrict__ x0_0, u16* __restrict__ x1_0)
{
  const long long total = 43845632LL;
  for (long long i = (long long)blockIdx.x * 256 + threadIdx.x; i < total;
       i += (long long)gridDim.x * 256) {
    if (i < 32768000LL) {                    // fc_w bf16, padded to 32000 rows
      int r = (int)(i >> 10), c = (int)(i & 1023);
      fcwb[i] = (r < 31999) ? f2bf(fcw[(long long)r * 1024 + c]) : (u16)0;
    } else if (i < 36962304LL) {             // encoder_outputs bf16
      long long j = i - 32768000LL; encb[j] = f2bf(enc[j]);
    } else if (i < 37486592LL) {             // W_enc bf16
      long long j = i - 36962304LL; wencb[j] = f2bf(wenc[j]);
    } else if (i < 38010880LL) {             // W_dec bf16
      long long j = i - 37486592LL; wdecb[j] = f2bf(wdec[j]);
    } else if (i < 40632320LL) {             // W0cat = [W_ih0 | W_hh0]  [1024][2560]
      long long j = i - 38010880LL;
      int r = (int)(j / 2560), c = (int)(j % 2560);
      w0cat[j] = f2bf(c < 1536 ? wih0[(long long)r * 1536 + c]
                               : whh0[(long long)r * 1024 + (c - 1536)]);
    } else if (i < 42729472LL) {             // W1cat = [W_ih1 | W_hh1]  [1024][2048]
      long long j = i - 40632320LL;
      int r = (int)(j >> 11), c = (int)(j & 2047);
      w1cat[j] = f2bf(c < 1024 ? wih1[(r << 10) + c] : whh1[(r << 10) + (c - 1024)]);
    } else if (i < 43778048LL) {             // embedding gather -> bf16 [2048][512]
      long long j = i - 42729472LL;
      int bt = (int)(j >> 9), c = (int)(j & 511);
      int y = yin[bt];
      embbt[j] = f2bf(emb[(long long)y * 512 + c]);
    } else if (i < 43779072LL) {             // bias0 = b_ih0 + b_hh0
      int j = (int)(i - 43778048LL); bias0[j] = bih0[j] + bhh0[j];
    } else if (i < 43780096LL) {             // bias1
      int j = (int)(i - 43779072LL); bias1[j] = bih1[j] + bhh1[j];
    } else if (i < 43812864LL) {             // h0 init -> x0[0][:,1536:]
      int j = (int)(i - 43780096LL); int b = j >> 10, c = j & 1023;
      x0_0[b * 2560 + 1536 + c] = f2bf(dih[j]);
    } else {                                 // h1 init -> x1[0][:,1024:]
      int j = (int)(i - 43812864LL); int b = j >> 10, c = j & 1023;
      x1_0[b * 2048 + 1024 + c] = f2bf(dih[32768 + j]);
    }
  }
}

// ---------------------------------------------------------------------------
// Generic 128x128-tile bf16 MFMA GEMM:  C[M][N] = A[M][K] * B[N][K]^T + bias
// ---------------------------------------------------------------------------
__global__ __launch_bounds__(256) void gemm128(
    const u16* __restrict__ A, const u16* __restrict__ Bm,
    const float* __restrict__ bias, float* __restrict__ C,
    int K, int ldc, int Nvalid, int ntN)
{
  __shared__ u16 As[128 * 32];
  __shared__ u16 Bs[128 * 32];
  const int tid = threadIdx.x;
  const int bid = blockIdx.x;
  const int tM = bid / ntN, tN = bid - tM * ntN;
  const int m0 = tM * 128, n0 = tN * 128;
  const int lane = tid & 63, wid = tid >> 6;
  const int wm = wid >> 1, wn = wid & 1;
  const int srow = tid >> 1, scol = (tid & 1) * 16;

  const u16* gA = A + (size_t)(m0 + srow) * K + scol;
  const u16* gB = Bm + (size_t)(n0 + srow) * K + scol;
  u16* sA = &As[srow * 32 + scol];
  u16* sB = &Bs[srow * 32 + scol];

  f32x4 acc[4][4];
#pragma unroll
  for (int i = 0; i < 4; ++i)
#pragma unroll
    for (int j = 0; j < 4; ++j) acc[i][j] = (f32x4){0, 0, 0, 0};

  const int aoff = (wm * 64 + (lane & 15)) * 32 + ((lane >> 4) << 3);
  const int boff = (wn * 64 + (lane & 15)) * 32 + ((lane >> 4) << 3);

  for (int k0 = 0; k0 < K; k0 += 32) {
    bf16x8 va0 = *(const bf16x8*)(gA + k0);
    bf16x8 va1 = *(const bf16x8*)(gA + k0 + 8);
    bf16x8 vb0 = *(const bf16x8*)(gB + k0);
    bf16x8 vb1 = *(const bf16x8*)(gB + k0 + 8);
    __syncthreads();
    *((bf16x8*)sA) = va0;  *((bf16x8*)(sA + 8)) = va1;
    *((bf16x8*)sB) = vb0;  *((bf16x8*)(sB + 8)) = vb1;
    __syncthreads();
    bf16x8 af[4], bfj[4];
#pragma unroll
    for (int i = 0; i < 4; ++i) af[i] = *(const bf16x8*)&As[aoff + i * 512];
#pragma unroll
    for (int j = 0; j < 4; ++j) bfj[j] = *(const bf16x8*)&Bs[boff + j * 512];
#pragma unroll
    for (int i = 0; i < 4; ++i)
#pragma unroll
      for (int j = 0; j < 4; ++j)
        acc[i][j] = MFMA_BF16(af[i], bfj[j], acc[i][j]);
  }

#pragma unroll
  for (int i = 0; i < 4; ++i) {
#pragma unroll
    for (int j = 0; j < 4; ++j) {
      int row = m0 + wm * 64 + i * 16 + ((lane >> 4) << 2);
      int cc = n0 + wn * 64 + j * 16 + (lane & 15);
      if (cc < Nvalid) {
        float bs = bias ? bias[cc] : 0.f;
#pragma unroll
        for (int jj = 0; jj < 4; ++jj)
          C[(size_t)(row + jj) * ldc + cc] = acc[i][j][jj] + bs;
      }
    }
  }
}

// ---------------------------------------------------------------------------
// Persistent recurrence kernel. Grid = 240 blocks x 256 threads, 1 block/CU.
// Roles: [0,16) DECP | [16,80) SCORE | [80,144) CTX | [144,208) H0 | [208,240) H1
// Dyn LDS: 8 KiB f32 scratch + role data (max CTX 130 KiB) = 141312 B.
// ---------------------------------------------------------------------------
__global__ __launch_bounds__(256, 1) void decoder_persistent(
    const u16* __restrict__ wdecb, const u16* __restrict__ w0cat,
    const u16* __restrict__ w1cat, const u16* __restrict__ encb,
    const float* __restrict__ encproj, const u16* __restrict__ embbt,
    const float* __restrict__ bias0, const float* __restrict__ bias1,
    const float* __restrict__ vw, const int* __restrict__ msk,
    float* __restrict__ decp, float* __restrict__ esc, float* __restrict__ psum,
    u16* __restrict__ x0, u16* __restrict__ x1, u16* __restrict__ h1all,
    float* __restrict__ outattn, u32* cnts)
{
  extern __shared__ char smem[];
  float* sc = (float*)smem;
  u16* role = (u16*)(smem + 8192);
  const int tid = threadIdx.x;
  const int bid = blockIdx.x;
  const int lane = tid & 63, wid = tid >> 6;
  u32* c_decp  = cnts;
  u32* c_score = cnts + 32;
  u32* c_ctx   = cnts + 64;
  u32* c_h0    = cnts + 96;
  u32* c_h1    = cnts + 128;

  if (bid < 16) {
    // ---------------- DECP: decp[32][512] = h1_prev @ W_dec^T ----------------
    const int n0 = bid * 32;
    {
      const int row = tid >> 3, c0 = (tid & 7) * 128;
#pragma unroll
      for (int i = 0; i < 16; ++i)
        *(bf16x8*)&role[row * 1032 + c0 + i * 8] =
            *(const bf16x8*)&wdecb[(size_t)(n0 + row) * 1024 + c0 + i * 8];
    }
    __syncthreads();
    const int mh = wid & 1, kh = wid >> 1;
    const int lrow = lane & 15, lk = (lane >> 4) << 3;
    for (int t = 0; t < 64; ++t) {
      wait_ge(c_h1, 32u * (u32)t);
      const u16* ar = x1 + (size_t)(t & 1) * X1SZ + 1024 +
                      (size_t)(mh * 16 + lrow) * 2048 + kh * 512 + lk;
      f32x4 ac0 = {0,0,0,0}, ac1 = {0,0,0,0};
      const int bb = kh * 512 + lk;
#pragma unroll 4
      for (int ks = 0; ks < 16; ++ks) {
        bf16x8 a  = *(const bf16x8*)(ar + ks * 32);
        bf16x8 b0 = *(const bf16x8*)&role[lrow * 1032 + bb + ks * 32];
        bf16x8 b1 = *(const bf16x8*)&role[(16 + lrow) * 1032 + bb + ks * 32];
        ac0 = MFMA_BF16(a, b0, ac0);
        ac1 = MFMA_BF16(a, b1, ac1);
      }
      __syncthreads();
      if (kh == 1) {
        *(f32x4*)&sc[(mh * 64 + lane) * 8]     = ac0;
        *(f32x4*)&sc[(mh * 64 + lane) * 8 + 4] = ac1;
      }
      __syncthreads();
      if (kh == 0) {
        f32x4 o0 = *(const f32x4*)&sc[(mh * 64 + lane) * 8];
        f32x4 o1 = *(const f32x4*)&sc[(mh * 64 + lane) * 8 + 4];
        const int rb = mh * 16 + ((lane >> 4) << 2);
        const int c0g = n0 + lrow, c1g = n0 + 16 + lrow;
#pragma unroll
        for (int j = 0; j < 4; ++j) {
          decp[(rb + j) * 512 + c0g] = ac0[j] + o0[j];
          decp[(rb + j) * 512 + c1g] = ac1[j] + o1[j];
        }
      }
      post_add(c_decp);
    }
  } else if (bid < 80) {
    // ---------------- SCORE: e[b][s] = exp(v . tanh(ep + dp)) ----------------
    const int ii = bid - 16, b = ii >> 1, sh = ii & 1;
    const int r = tid >> 2, q = tid & 3;
    {
      const float* g = encproj + (size_t)(b * 128 + sh * 64 + r) * 512 + q * 128;
#pragma unroll 4
      for (int i = 0; i < 32; ++i) {
        f32x4 v = *(const f32x4*)(g + i * 4);
        int base = r * 520 + q * 128 + i * 4;
        role[base + 0] = f2bf(v[0]); role[base + 1] = f2bf(v[1]);
        role[base + 2] = f2bf(v[2]); role[base + 3] = f2bf(v[3]);
      }
      sc[512 + tid] = vw[tid];
      sc[768 + tid] = vw[256 + tid];
      if (tid < 64) sc[1024 + tid] = (float)msk[b * 128 + sh * 64 + tid];
    }
    __syncthreads();
    for (int t = 0; t < 64; ++t) {
      wait_ge(c_decp, 16u * (u32)(t + 1));
      sc[tid]       = decp[b * 512 + tid];
      sc[256 + tid] = decp[b * 512 + 256 + tid];
      __syncthreads();
      float acc = 0.f;
#pragma unroll 2
      for (int i = 0; i < 16; ++i) {
        bf16x8 ev = *(const bf16x8*)&role[r * 520 + q * 128 + i * 8];
#pragma unroll
        for (int j = 0; j < 8; ++j) {
          int a = q * 128 + i * 8 + j;
          float x = bf2f((u16)ev[j]) + sc[a];
          acc += sc[512 + a] * tanh_fast(x);
        }
      }
      acc += __shfl_xor(acc, 1);
      acc += __shfl_xor(acc, 2);
      float e = 0.f;
      if (q == 0) {
        e = (sc[1024 + r] != 0.f) ? __expf(acc) : 0.f;
        esc[b * 128 + sh * 64 + r] = e;
      }
      float ee = e;
#pragma unroll
      for (int off = 1; off < 64; off <<= 1) ee += __shfl_xor(ee, off);
      if (lane == 0) sc[1152 + wid] = ee;
      __syncthreads();
      if (tid == 0) psum[b * 2 + sh] = sc[1152] + sc[1153] + sc[1154] + sc[1155];
      post_add(c_score);
    }
  } else if (bid < 144) {
    // ---------------- CTX: softmax-normalize + context + emb copy ------------
    const int ii = bid - 80, b = ii >> 1, eh = ii & 1;
    {
      const int s = tid >> 1, half = tid & 1;
#pragma unroll 4
      for (int i = 0; i < 32; ++i)
        *(bf16x8*)&role[s * 520 + half * 256 + i * 8] =
            *(const bf16x8*)&encb[(size_t)(b * 128 + s) * 1024 + eh * 512 + half * 256 + i * 8];
    }
    __syncthreads();
    for (int t = 0; t < 64; ++t) {
      wait_ge(c_score, 64u * (u32)(t + 1));
      if (tid < 128) sc[tid] = esc[b * 128 + tid];
      if (tid == 128) sc[128] = psum[b * 2] + psum[b * 2 + 1];
      __syncthreads();
      float tot = sc[128];
      if (tid < 128) {
        float att = (tot > 0.f) ? sc[tid] / tot : (1.f / 128.f);
        sc[256 + tid] = att;
        if (eh == 0) outattn[(size_t)(b * 64 + t) * 128 + tid] = att;
      }
      __syncthreads();
      float a0 = 0.f, a1 = 0.f;
#pragma unroll 8
      for (int s = 0; s < 128; ++s) {
        u32 w = *(const u32*)&role[s * 520 + tid * 2];
        float wa = sc[256 + s];
        a0 += wa * bf2f((u16)(w & 0xffffu));
        a1 += wa * bf2f((u16)(w >> 16));
      }
      u16* x0w = x0 + (size_t)(t & 1) * X0SZ + b * 2560;
      u32 pk = (u32)f2bf(a0) | ((u32)f2bf(a1) << 16);
      *(u32*)(x0w + 512 + eh * 512 + tid * 2) = pk;
      if (eh == 0) {
        u32 v = ((const u32*)embbt)[(size_t)(b * 64 + t) * 256 + tid];
        *(u32*)(x0w + tid * 2) = v;
      }
      post_add(c_ctx);
    }
  } else if (bid < 208) {
    // ---------------- H0: h0 = tanh(x0 @ W0cat^T + bias0) --------------------
    const int h = bid - 144, n0 = h * 16;
    {
      const int row = tid >> 4, seg = (tid & 15) * 160;
#pragma unroll 4
      for (int i = 0; i < 20; ++i)
        *(bf16x8*)&role[row * 2568 + seg + i * 8] =
            *(const bf16x8*)&w0cat[(size_t)(n0 + row) * 2560 + seg + i * 8];
      if (tid < 16) sc[1100 + tid] = bias0[n0 + tid];
    }
    __syncthreads();
    const int mh = wid & 1, kh = wid >> 1;
    const int lrow = lane & 15, lk = (lane >> 4) << 3;
    for (int t = 0; t < 64; ++t) {
      wait_ge(c_ctx, 64u * (u32)(t + 1));
      const u16* ar = x0 + (size_t)(t & 1) * X0SZ +
                      (size_t)(mh * 16 + lrow) * 2560 + kh * 1280 + lk;
      f32x4 acc = {0,0,0,0};
      const int bb = kh * 1280 + lk;
#pragma unroll 4
      for (int ks = 0; ks < 40; ++ks) {
        bf16x8 a  = *(const bf16x8*)(ar + ks * 32);
        bf16x8 bv = *(const bf16x8*)&role[lrow * 2568 + bb + ks * 32];
        acc = MFMA_BF16(a, bv, acc);
      }
      __syncthreads();
      if (kh == 1) *(f32x4*)&sc[(mh * 64 + lane) * 4] = acc;
      __syncthreads();
      if (kh == 0) {
        f32x4 o = *(const f32x4*)&sc[(mh * 64 + lane) * 4];
        const int rb = mh * 16 + ((lane >> 4) << 2);
        const int cg = n0 + lrow;
        const float bs = sc[1100 + lrow];
        u16* x1w = x1 + (size_t)(t & 1) * X1SZ;
        u16* x0n = x0 + (size_t)((t + 1) & 1) * X0SZ;
#pragma unroll
        for (int j = 0; j < 4; ++j) {
          u16 v = f2bf(tanh_fast(acc[j] + o[j] + bs));
          x1w[(size_t)(rb + j) * 2048 + cg] = v;
          x0n[(size_t)(rb + j) * 2560 + 1536 + cg] = v;
        }
      }
      post_add(c_h0);
    }
  } else {
    // ---------------- H1: h1 = tanh(x1 @ W1cat^T + bias1) --------------------
    const int h = bid - 208, n0 = h * 32;
    {
      const int row = tid >> 3, seg = (tid & 7) * 256;
#pragma unroll 4
      for (int i = 0; i < 32; ++i)
        *(bf16x8*)&role[row * 2056 + seg + i * 8] =
            *(const bf16x8*)&w1cat[(size_t)(n0 + row) * 2048 + seg + i * 8];
      if (tid < 32) sc[1100 + tid] = bias1[n0 + tid];
    }
    __syncthreads();
    const int mh = wid & 1, kh = wid >> 1;
    const int lrow = lane & 15, lk = (lane >> 4) << 3;
    for (int t = 0; t < 64; ++t) {
      wait_ge(c_h0, 64u * (u32)(t + 1));
      const u16* ar = x1 + (size_t)(t & 1) * X1SZ +
                      (size_t)(mh * 16 + lrow) * 2048 + kh * 1024 + lk;
      f32x4 ac0 = {0,0,0,0}, ac1 = {0,0,0,0};
      const int bb = kh * 1024 + lk;
#pragma unroll 4
      for (int ks = 0; ks < 32; ++ks) {
        bf16x8 a  = *(const bf16x8*)(ar + ks * 32);
        bf16x8 b0 = *(const bf16x8*)&role[lrow * 2056 + bb + ks * 32];
        bf16x8 b1 = *(const bf16x8*)&role[(16 + lrow) * 2056 + bb + ks * 32];
        ac0 = MFMA_BF16(a, b0, ac0);
        ac1 = MFMA_BF16(a, b1, ac1);
      }
      __syncthreads();
      if (kh == 1) {
        *(f32x4*)&sc[(mh * 64 + lane) * 8]     = ac0;
        *(f32x4*)&sc[(mh * 64 + lane) * 8 + 4] = ac1;
      }
      __syncthreads();
      if (kh == 0) {
        f32x4 o0 = *(const f32x4*)&sc[(mh * 64 + lane) * 8];
        f32x4 o1 = *(const f32x4*)&sc[(mh * 64 + lane) * 8 + 4];
        const int rb = mh * 16 + ((lane >> 4) << 2);
        const int c0g = n0 + lrow, c1g = n0 + 16 + lrow;
        const float bs0 = sc[1100 + lrow], bs1 = sc[1100 + 16 + lrow];
        u16* x1n = x1 + (size_t)((t + 1) & 1) * X1SZ;
#pragma unroll
        for (int j = 0; j < 4; ++j) {
          int row = rb + j;
          u16 v0 = f2bf(tanh_fast(ac0[j] + o0[j] + bs0));
          u16 v1 = f2bf(tanh_fast(ac1[j] + o1[j] + bs1));
          x1n[(size_t)row * 2048 + 1024 + c0g] = v0;
          x1n[(size_t)row * 2048 + 1024 + c1g] = v1;
          h1all[(size_t)(row * 64 + t) * 1024 + c0g] = v0;
          h1all[(size_t)(row * 64 + t) * 1024 + c1g] = v1;
        }
      }
      post_add(c_h1);
    }
  }
}

// ---------------------------------------------------------------------------
extern "C" void kernel_launch(void* const* d_in, const int* in_sizes, int n_in,
                              void* d_out, int out_size, void* d_ws, size_t ws_size,
                              hipStream_t stream)
{
  const int*   yin  = (const int*)d_in[0];
  const float* enc  = (const float*)d_in[1];
  const float* dih  = (const float*)d_in[2];
  const int*   msk  = (const int*)d_in[3];
  const float* emb  = (const float*)d_in[4];
  const float* wenc = (const float*)d_in[5];
  const float* wdec = (const float*)d_in[6];
  const float* vw   = (const float*)d_in[7];
  const float* wih0 = (const float*)d_in[8];
  const float* whh0 = (const float*)d_in[9];
  const float* bih0 = (const float*)d_in[10];
  const float* bhh0 = (const float*)d_in[11];
  const float* wih1 = (const float*)d_in[12];
  const float* whh1 = (const float*)d_in[13];
  const float* bih1 = (const float*)d_in[14];
  const float* bhh1 = (const float*)d_in[15];
  const float* fcw  = (const float*)d_in[16];
  const float* fcb  = (const float*)d_in[17];

  char* ws = (char*)d_ws;
  size_t off = 0;
  auto alloc = [&](size_t bytes) {
    char* p = ws + off; off += (bytes + 255) & ~(size_t)255; return p;
  };
  u16*   fcwb    = (u16*)alloc(32768000ULL * 2);
  u16*   encb    = (u16*)alloc(4194304ULL * 2);
  u16*   wencb   = (u16*)alloc(524288ULL * 2);
  u16*   wdecb   = (u16*)alloc(524288ULL * 2);
  u16*   w0cat   = (u16*)alloc(2621440ULL * 2);
  u16*   w1cat   = (u16*)alloc(2097152ULL * 2);
  u16*   embbt   = (u16*)alloc(1048576ULL * 2);
  float* encproj = (float*)alloc(2097152ULL * 4);
  float* decp    = (float*)alloc(16384ULL * 4);
  float* bias0   = (float*)alloc(1024ULL * 4);
  float* bias1   = (float*)alloc(1024ULL * 4);
  u16*   x0buf   = (u16*)alloc(2ULL * X0SZ * 2);
  u16*   x1buf   = (u16*)alloc(2ULL * X1SZ * 2);
  u16*   h1all   = (u16*)alloc(2097152ULL * 2);
  float* escb    = (float*)alloc(4096ULL * 4);
  float* psumb   = (float*)alloc(64ULL * 4);
  u32*   cnts    = (u32*)alloc(1024ULL);
  if (off > ws_size) return;  // workspace too small -> visible failure

  float* outlog  = (float*)d_out;                 // [2048][31999]
  float* outattn = outlog + 65533952ULL;          // [32][64][128]

  hipMemsetAsync(cnts, 0, 1024, stream);

  prep_kernel<<<2048, 256, 0, stream>>>(
      fcw, enc, wenc, wdec, wih0, whh0, wih1, whh1,
      bih0, bhh0, bih1, bhh1, emb, yin, dih,
      fcwb, encb, wencb, wdecb, w0cat, w1cat, embbt, bias0, bias1,
      x0buf, x1buf);

  // enc_proj: [4096][512] = encb[4096][1024] @ wencb[512][1024]^T
  gemm128<<<32 * 4, 256, 0, stream>>>(encb, wencb, nullptr, encproj,
                                      1024, 512, 512, 4);

  // persistent recurrence over T=64 steps
  (void)hipFuncSetAttribute((const void*)decoder_persistent,
                            hipFuncAttributeMaxDynamicSharedMemorySize, 141312);
  decoder_persistent<<<240, 256, 141312, stream>>>(
      wdecb, w0cat, w1cat, encb, encproj, embbt, bias0, bias1,
      vw, msk, decp, escb, psumb, x0buf, x1buf, h1all, outattn, cnts);

  // logits: [2048][31999] = h1all[2048][1024] @ fcwb[32000][1024]^T + fc_b
  gemm128<<<16 * 250, 256, 0, stream>>>(h1all, fcwb, fcb, outlog,
                                        1024, 31999, 31999, 250);
}

// Round 3
// 2477.362 us; speedup vs baseline: 2.1224x; 1.4019x over previous
//
#include <hip/hip_runtime.h>

typedef unsigned short u16;
typedef unsigned int u32;
typedef __attribute__((ext_vector_type(8))) short bf16x8;
typedef __attribute__((ext_vector_type(4))) float f32x4;

#define MFMA_BF16(a,b,c) __builtin_amdgcn_mfma_f32_16x16x32_bf16((a),(b),(c),0,0,0)

__device__ __forceinline__ u16 f2bf(float f) {
  union { float f; u32 u; } v; v.f = f;
  u32 r = v.u + 0x7FFFu + ((v.u >> 16) & 1u);
  return (u16)(r >> 16);
}
__device__ __forceinline__ float bf2f(u16 h) {
  union { u32 u; float f; } v; v.u = ((u32)h) << 16; return v.f;
}
__device__ __forceinline__ float tanh_fast(float x) {
  float e = __expf(2.0f * x);
  return 1.0f - 2.0f / (e + 1.0f);
}
__device__ __forceinline__ float exp2_fast(float x) {
  float r; asm("v_exp_f32 %0, %1" : "=v"(r) : "v"(x)); return r;
}
__device__ __forceinline__ float rcp_fast(float x) {
  float r; asm("v_rcp_f32 %0, %1" : "=v"(r) : "v"(x)); return r;
}

// ---- coherent (cross-XCD) loads/stores: bypass non-coherent L2 -------------
__device__ __forceinline__ void issue_lcoh(bf16x8& v, const u16* p) {
  asm volatile("global_load_dwordx4 %0, %1, off sc0 sc1" : "=v"(v) : "v"(p));
}
__device__ __forceinline__ void issue_lcoh_f4(f32x4& v, const float* p) {
  asm volatile("global_load_dwordx4 %0, %1, off sc0 sc1" : "=v"(v) : "v"(p));
}
__device__ __forceinline__ float lcoh_f32(const float* p) {
  float v;
  asm volatile("global_load_dword %0, %1, off sc0 sc1" : "=v"(v) : "v"(p));
  return v;
}
__device__ __forceinline__ void vm_wait0() {
  asm volatile("s_waitcnt vmcnt(0)" ::: "memory");
  __builtin_amdgcn_sched_barrier(0);
}
__device__ __forceinline__ void scoh_f32(float* p, float v) {
  asm volatile("global_store_dword %0, %1, off sc0 sc1" :: "v"(p), "v"(v) : "memory");
}
__device__ __forceinline__ void scoh_u32(u32* p, u32 v) {
  asm volatile("global_store_dword %0, %1, off sc0 sc1" :: "v"(p), "v"(v) : "memory");
}
__device__ __forceinline__ void scoh_u16(u16* p, u16 v) {
  u32 w = v;
  asm volatile("global_store_short %0, %1, off sc0 sc1" :: "v"(p), "v"(w) : "memory");
}

// ---- handoff primitives: NO fences (data goes via sc0sc1 path) -------------
__device__ __forceinline__ void wait_ge(u32* c, u32 target) {
  if (threadIdx.x == 0) {
    while (__hip_atomic_load(c, __ATOMIC_RELAXED, __HIP_MEMORY_SCOPE_AGENT) < target)
      __builtin_amdgcn_s_sleep(1);
  }
  __syncthreads();
}
__device__ __forceinline__ void post_add(u32* c) {
  asm volatile("s_waitcnt vmcnt(0)" ::: "memory");  // drain coh stores
  __syncthreads();
  if (threadIdx.x == 0)
    __hip_atomic_fetch_add(c, 1u, __ATOMIC_RELAXED, __HIP_MEMORY_SCOPE_AGENT);
}

// ---------------------------------------------------------------------------
// Prep: bf16 conversions, weight concat/re-layout, embedding gather, init
// ---------------------------------------------------------------------------
__global__ void prep_kernel(
    const float* __restrict__ fcw, const float* __restrict__ enc,
    const float* __restrict__ wenc, const float* __restrict__ wdec,
    const float* __restrict__ wih0, const float* __restrict__ whh0,
    const float* __restrict__ wih1, const float* __restrict__ whh1,
    const float* __restrict__ bih0, const float* __restrict__ bhh0,
    const float* __restrict__ bih1, const float* __restrict__ bhh1,
    const float* __restrict__ emb, const int* __restrict__ yin,
    const float* __restrict__ dih,
    u16* __restrict__ fcwb, u16* __restrict__ encb, u16* __restrict__ wencb,
    u16* __restrict__ wdecb, u16* __restrict__ w0cat, u16* __restrict__ w1cat,
    u16* __restrict__ embbt, float* __restrict__ bias0, float* __restrict__ bias1,
    u16* __restrict__ h0st0, u16* __restrict__ h1st0)
{
  const float SCL = 2.8853900817779268f;   // 2*log2(e): tanh-arg prescale
  const long long total = 43845632LL;
  for (long long i = (long long)blockIdx.x * 256 + threadIdx.x; i < total;
       i += (long long)gridDim.x * 256) {
    if (i < 32768000LL) {                    // fc_w bf16, padded to 32000 rows
      int r = (int)(i >> 10), c = (int)(i & 1023);
      fcwb[i] = (r < 31999) ? f2bf(fcw[(long long)r * 1024 + c]) : (u16)0;
    } else if (i < 36962304LL) {             // encoder_outputs bf16
      long long j = i - 32768000LL; encb[j] = f2bf(enc[j]);
    } else if (i < 37486592LL) {             // W_enc bf16, prescaled
      long long j = i - 36962304LL; wencb[j] = f2bf(wenc[j] * SCL);
    } else if (i < 38010880LL) {             // W_dec bf16, prescaled
      long long j = i - 37486592LL; wdecb[j] = f2bf(wdec[j] * SCL);
    } else if (i < 40632320LL) {             // W0cat [1024][2560]: [emb|h0prev|ctx]
      long long j = i - 38010880LL;
      int r = (int)(j / 2560), c = (int)(j % 2560);
      float v;
      if (c < 512)       v = wih0[(long long)r * 1536 + c];
      else if (c < 1536) v = whh0[(long long)r * 1024 + (c - 512)];
      else               v = wih0[(long long)r * 1536 + (c - 1024)];
      w0cat[j] = f2bf(v);
    } else if (i < 42729472LL) {             // W1cat [1024][2048]: [h0|h1prev]
      long long j = i - 40632320LL;
      int r = (int)(j >> 11), c = (int)(j & 2047);
      w1cat[j] = f2bf(c < 1024 ? wih1[(r << 10) + c] : whh1[(r << 10) + (c - 1024)]);
    } else if (i < 43778048LL) {             // embedding gather -> bf16 [2048][512]
      long long j = i - 42729472LL;
      int bt = (int)(j >> 9), c = (int)(j & 511);
      int y = yin[bt];
      embbt[j] = f2bf(emb[(long long)y * 512 + c]);
    } else if (i < 43779072LL) {             // bias0 = b_ih0 + b_hh0
      int j = (int)(i - 43778048LL); bias0[j] = bih0[j] + bhh0[j];
    } else if (i < 43780096LL) {             // bias1
      int j = (int)(i - 43779072LL); bias1[j] = bih1[j] + bhh1[j];
    } else if (i < 43812864LL) {             // h0 init [32][1024]
      int j = (int)(i - 43780096LL); h0st0[j] = f2bf(dih[j]);
    } else {                                 // h1 init [32][1024]
      int j = (int)(i - 43812864LL); h1st0[j] = f2bf(dih[32768 + j]);
    }
  }
}

// ---------------------------------------------------------------------------
// Generic 128x128-tile bf16 MFMA GEMM:  C[M][N] = A[M][K] * B[N][K]^T + bias
// ---------------------------------------------------------------------------
__global__ __launch_bounds__(256) void gemm128(
    const u16* __restrict__ A, const u16* __restrict__ Bm,
    const float* __restrict__ bias, float* __restrict__ C,
    int K, int ldc, int Nvalid, int ntN)
{
  __shared__ u16 As[128 * 32];
  __shared__ u16 Bs[128 * 32];
  const int tid = threadIdx.x;
  const int bid = blockIdx.x;
  const int tM = bid / ntN, tN = bid - tM * ntN;
  const int m0 = tM * 128, n0 = tN * 128;
  const int lane = tid & 63, wid = tid >> 6;
  const int wm = wid >> 1, wn = wid & 1;
  const int srow = tid >> 1, scol = (tid & 1) * 16;

  const u16* gA = A + (size_t)(m0 + srow) * K + scol;
  const u16* gB = Bm + (size_t)(n0 + srow) * K + scol;
  u16* sA = &As[srow * 32 + scol];
  u16* sB = &Bs[srow * 32 + scol];

  f32x4 acc[4][4];
#pragma unroll
  for (int i = 0; i < 4; ++i)
#pragma unroll
    for (int j = 0; j < 4; ++j) acc[i][j] = (f32x4){0, 0, 0, 0};

  const int aoff = (wm * 64 + (lane & 15)) * 32 + ((lane >> 4) << 3);
  const int boff = (wn * 64 + (lane & 15)) * 32 + ((lane >> 4) << 3);

  for (int k0 = 0; k0 < K; k0 += 32) {
    bf16x8 va0 = *(const bf16x8*)(gA + k0);
    bf16x8 va1 = *(const bf16x8*)(gA + k0 + 8);
    bf16x8 vb0 = *(const bf16x8*)(gB + k0);
    bf16x8 vb1 = *(const bf16x8*)(gB + k0 + 8);
    __syncthreads();
    *((bf16x8*)sA) = va0;  *((bf16x8*)(sA + 8)) = va1;
    *((bf16x8*)sB) = vb0;  *((bf16x8*)(sB + 8)) = vb1;
    __syncthreads();
    bf16x8 af[4], bfj[4];
#pragma unroll
    for (int i = 0; i < 4; ++i) af[i] = *(const bf16x8*)&As[aoff + i * 512];
#pragma unroll
    for (int j = 0; j < 4; ++j) bfj[j] = *(const bf16x8*)&Bs[boff + j * 512];
#pragma unroll
    for (int i = 0; i < 4; ++i)
#pragma unroll
      for (int j = 0; j < 4; ++j)
        acc[i][j] = MFMA_BF16(af[i], bfj[j], acc[i][j]);
  }

#pragma unroll
  for (int i = 0; i < 4; ++i) {
#pragma unroll
    for (int j = 0; j < 4; ++j) {
      int row = m0 + wm * 64 + i * 16 + ((lane >> 4) << 2);
      int cc = n0 + wn * 64 + j * 16 + (lane & 15);
      if (cc < Nvalid) {
        float bs = bias ? bias[cc] : 0.f;
#pragma unroll
        for (int jj = 0; jj < 4; ++jj)
          C[(size_t)(row + jj) * ldc + cc] = acc[i][j][jj] + bs;
      }
    }
  }
}

// ---------------------------------------------------------------------------
// Persistent recurrence. Grid = 240x256, 1 block/CU.
// Roles: [0,16) DECP | [16,80) SCORE | [80,144) CTX | [144,208) H0 | [208,240) H1
// Handoff data via sc0sc1 coherent ld/st; flags via relaxed agent atomics.
// ---------------------------------------------------------------------------
__global__ __launch_bounds__(256, 1) void decoder_persistent(
    const u16* __restrict__ wdecb, const u16* __restrict__ w0cat,
    const u16* __restrict__ w1cat, const u16* __restrict__ encb,
    const float* __restrict__ encproj, const u16* __restrict__ embbt,
    const float* __restrict__ bias0, const float* __restrict__ bias1,
    const float* __restrict__ vw, const int* __restrict__ msk,
    float* __restrict__ decp, float* __restrict__ esc, float* __restrict__ psum,
    u16* __restrict__ ctxbuf, u16* __restrict__ h0st, u16* __restrict__ h1st,
    u16* __restrict__ h1all, float* __restrict__ outattn, u32* cnts)
{
  extern __shared__ char smem[];
  float* sc = (float*)smem;
  u16* role = (u16*)(smem + 8192);
  const int tid = threadIdx.x;
  const int bid = blockIdx.x;
  const int lane = tid & 63, wid = tid >> 6;
  u32* c_decp  = cnts;
  u32* c_score = cnts + 32;
  u32* c_ctx   = cnts + 64;
  u32* c_h0    = cnts + 96;
  u32* c_h1    = cnts + 128;

  if (bid < 16) {
    // ---------------- DECP: decp[32][512] = h1_prev @ Wdec'^T ----------------
    const int n0 = bid * 32;
    {
      const int row = tid >> 3, c0 = (tid & 7) * 128;
#pragma unroll
      for (int i = 0; i < 16; ++i)
        *(bf16x8*)&role[row * 1032 + c0 + i * 8] =
            *(const bf16x8*)&wdecb[(size_t)(n0 + row) * 1024 + c0 + i * 8];
    }
    __syncthreads();
    const int mh = wid & 1, kh = wid >> 1;
    const int lrow = lane & 15, lk = (lane >> 4) << 3;
    const int b = mh * 16 + lrow;
    for (int t = 0; t < 64; ++t) {
      wait_ge(c_h1, 32u * (u32)t);
      const u16* hb = h1st + (size_t)(t & 1) * 32768 + (size_t)b * 1024 + kh * 512 + lk;
      bf16x8 av[16];
#pragma unroll
      for (int ks = 0; ks < 16; ++ks) issue_lcoh(av[ks], hb + ks * 32);
      vm_wait0();
      f32x4 ac0 = {0,0,0,0}, ac1 = {0,0,0,0};
      const int bb = kh * 512 + lk;
#pragma unroll
      for (int ks = 0; ks < 16; ++ks) {
        bf16x8 b0 = *(const bf16x8*)&role[lrow * 1032 + bb + ks * 32];
        bf16x8 b1 = *(const bf16x8*)&role[(16 + lrow) * 1032 + bb + ks * 32];
        ac0 = MFMA_BF16(av[ks], b0, ac0);
        ac1 = MFMA_BF16(av[ks], b1, ac1);
      }
      __syncthreads();
      if (kh == 1) {
        *(f32x4*)&sc[(mh * 64 + lane) * 8]     = ac0;
        *(f32x4*)&sc[(mh * 64 + lane) * 8 + 4] = ac1;
      }
      __syncthreads();
      if (kh == 0) {
        f32x4 o0 = *(const f32x4*)&sc[(mh * 64 + lane) * 8];
        f32x4 o1 = *(const f32x4*)&sc[(mh * 64 + lane) * 8 + 4];
        const int rb = mh * 16 + ((lane >> 4) << 2);
        const int c0g = n0 + lrow, c1g = n0 + 16 + lrow;
#pragma unroll
        for (int j = 0; j < 4; ++j) {
          scoh_f32(decp + (rb + j) * 512 + c0g, ac0[j] + o0[j]);
          scoh_f32(decp + (rb + j) * 512 + c1g, ac1[j] + o1[j]);
        }
      }
      post_add(c_decp);
    }
  } else if (bid < 80) {
    // ---------------- SCORE: e[b][s] = exp(v . tanh-hat(ep'+dp')) ------------
    const int ii = bid - 16, b = ii >> 1, sh = ii & 1;
    const int r = tid >> 2, q = tid & 3;
    {
      const float* g = encproj + (size_t)(b * 128 + sh * 64 + r) * 512 + q * 128;
#pragma unroll 4
      for (int i = 0; i < 32; ++i) {
        f32x4 v = *(const f32x4*)(g + i * 4);
        int base = r * 520 + q * 128 + i * 4;
        role[base + 0] = f2bf(v[0]); role[base + 1] = f2bf(v[1]);
        role[base + 2] = f2bf(v[2]); role[base + 3] = f2bf(v[3]);
      }
      sc[512 + tid] = vw[tid];
      sc[768 + tid] = vw[256 + tid];
      if (tid < 64) sc[1024 + tid] = (float)msk[b * 128 + sh * 64 + tid];
    }
    __syncthreads();
    for (int t = 0; t < 64; ++t) {
      wait_ge(c_decp, 16u * (u32)(t + 1));
      if (tid < 128) {
        f32x4 v; issue_lcoh_f4(v, decp + b * 512 + tid * 4);
        vm_wait0();
        *(f32x4*)&sc[tid * 4] = v;
      }
      __syncthreads();
      float acc = 0.f;
#pragma unroll 2
      for (int i = 0; i < 16; ++i) {
        bf16x8 ev = *(const bf16x8*)&role[r * 520 + q * 128 + i * 8];
#pragma unroll
        for (int j = 0; j < 8; ++j) {
          int a = q * 128 + i * 8 + j;
          float x = bf2f((u16)ev[j]) + sc[a];      // prescaled by 2*log2e
          float e2 = exp2_fast(x);                  // = exp(2x_true)
          acc = fmaf(sc[512 + a], 1.0f - 2.0f * rcp_fast(e2 + 1.0f), acc);
        }
      }
      acc += __shfl_xor(acc, 1);
      acc += __shfl_xor(acc, 2);
      float e = 0.f;
      if (q == 0) {
        e = (sc[1024 + r] != 0.f) ? __expf(acc) : 0.f;
        scoh_f32(esc + b * 128 + sh * 64 + r, e);
      }
      float ee = e;
#pragma unroll
      for (int off = 1; off < 64; off <<= 1) ee += __shfl_xor(ee, off);
      if (lane == 0) sc[1152 + wid] = ee;
      __syncthreads();
      if (tid == 0)
        scoh_f32(psum + b * 2 + sh, sc[1152] + sc[1153] + sc[1154] + sc[1155]);
      post_add(c_score);
    }
  } else if (bid < 144) {
    // ---------------- CTX: normalize + context + attn out --------------------
    const int ii = bid - 80, b = ii >> 1, eh = ii & 1;
    {
      const int s = tid >> 1, half = tid & 1;
#pragma unroll 4
      for (int i = 0; i < 32; ++i)
        *(bf16x8*)&role[s * 520 + half * 256 + i * 8] =
            *(const bf16x8*)&encb[(size_t)(b * 128 + s) * 1024 + eh * 512 + half * 256 + i * 8];
    }
    __syncthreads();
    for (int t = 0; t < 64; ++t) {
      wait_ge(c_score, 64u * (u32)(t + 1));
      if (tid < 32) {
        f32x4 v; issue_lcoh_f4(v, esc + b * 128 + tid * 4);
        vm_wait0();
        *(f32x4*)&sc[tid * 4] = v;
      } else if (tid == 32) {
        float p0 = lcoh_f32(psum + b * 2);
        float p1 = lcoh_f32(psum + b * 2 + 1);
        vm_wait0();
        sc[128] = p0; sc[129] = p1;
      }
      __syncthreads();
      float tot = sc[128] + sc[129];
      if (tid < 128) {
        float att = (tot > 0.f) ? sc[tid] * rcp_fast(tot) : 0.0078125f;
        sc[256 + tid] = att;
        if (eh == 0) outattn[(size_t)(b * 64 + t) * 128 + tid] = att;
      }
      __syncthreads();
      float a0 = 0.f, a1 = 0.f;
#pragma unroll 8
      for (int s = 0; s < 128; ++s) {
        u32 w = *(const u32*)&role[s * 520 + tid * 2];
        float wa = sc[256 + s];
        a0 += wa * bf2f((u16)(w & 0xffffu));
        a1 += wa * bf2f((u16)(w >> 16));
      }
      u32 pk = (u32)f2bf(a0) | ((u32)f2bf(a1) << 16);
      scoh_u32((u32*)(ctxbuf + (size_t)(t & 1) * 32768 + (size_t)b * 1024 + eh * 512 + tid * 2), pk);
      post_add(c_ctx);
    }
  } else if (bid < 208) {
    // ---------------- H0: h0 = tanh(x0 @ W0cat^T + bias0) --------------------
    // K layout: [emb 0..511 | h0prev 512..1535 | ctx 1536..2559]
    const int h = bid - 144, n0 = h * 16;
    {
      const int row = tid >> 4, seg = (tid & 15) * 160;
#pragma unroll 4
      for (int i = 0; i < 20; ++i)
        *(bf16x8*)&role[row * 2568 + seg + i * 8] =
            *(const bf16x8*)&w0cat[(size_t)(n0 + row) * 2560 + seg + i * 8];
      if (tid < 16) sc[1100 + tid] = bias0[n0 + tid];
    }
    __syncthreads();
    const int mh = wid & 1, kh = wid >> 1;
    const int lrow = lane & 15, lk = (lane >> 4) << 3;
    const int b = mh * 16 + lrow;
    for (int t = 0; t < 64; ++t) {
      wait_ge(c_h0, 64u * (u32)t);   // h0prev ready (previous step complete)
      f32x4 acc = {0,0,0,0};
      if (kh == 0) {
        // emb slices 0..15 (static, plain loads)
        const u16* eb = embbt + (size_t)(b * 64 + t) * 512 + lk;
        bf16x8 av[16];
#pragma unroll
        for (int ks = 0; ks < 16; ++ks) av[ks] = *(const bf16x8*)(eb + ks * 32);
#pragma unroll
        for (int ks = 0; ks < 16; ++ks)
          acc = MFMA_BF16(av[ks], *(const bf16x8*)&role[lrow * 2568 + ks * 32 + lk], acc);
      } else {
        // h0prev slices 16..47 (coherent)
        const u16* hb = h0st + (size_t)(t & 1) * 32768 + (size_t)b * 1024 + lk;
        bf16x8 av[32];
#pragma unroll
        for (int ks = 0; ks < 32; ++ks) issue_lcoh(av[ks], hb + ks * 32);
        vm_wait0();
#pragma unroll
        for (int ks = 0; ks < 32; ++ks)
          acc = MFMA_BF16(av[ks], *(const bf16x8*)&role[lrow * 2568 + (16 + ks) * 32 + lk], acc);
      }
      wait_ge(c_ctx, 64u * (u32)(t + 1));
      {
        // ctx slices: kh=0 -> 48..63 (cols 0..511), kh=1 -> 64..79 (512..1023)
        const u16* cb = ctxbuf + (size_t)(t & 1) * 32768 + (size_t)b * 1024 + kh * 512 + lk;
        bf16x8 cv[16];
#pragma unroll
        for (int ks = 0; ks < 16; ++ks) issue_lcoh(cv[ks], cb + ks * 32);
        vm_wait0();
#pragma unroll
        for (int ks = 0; ks < 16; ++ks)
          acc = MFMA_BF16(cv[ks], *(const bf16x8*)&role[lrow * 2568 + (48 + kh * 16 + ks) * 32 + lk], acc);
      }
      __syncthreads();
      if (kh == 1) *(f32x4*)&sc[(mh * 64 + lane) * 4] = acc;
      __syncthreads();
      if (kh == 0) {
        f32x4 o = *(const f32x4*)&sc[(mh * 64 + lane) * 4];
        const int rb = mh * 16 + ((lane >> 4) << 2);
        const int cg = n0 + lrow;
        const float bs = sc[1100 + lrow];
        u16* hw = h0st + (size_t)((t + 1) & 1) * 32768;
#pragma unroll
        for (int j = 0; j < 4; ++j) {
          u16 v = f2bf(tanh_fast(acc[j] + o[j] + bs));
          scoh_u16(hw + (size_t)(rb + j) * 1024 + cg, v);
        }
      }
      post_add(c_h0);
    }
  } else {
    // ---------------- H1: h1 = tanh([h0|h1prev] @ W1cat^T + bias1) ----------
    const int h = bid - 208, n0 = h * 32;
    {
      const int row = tid >> 3, seg = (tid & 7) * 256;
#pragma unroll 4
      for (int i = 0; i < 32; ++i)
        *(bf16x8*)&role[row * 2056 + seg + i * 8] =
            *(const bf16x8*)&w1cat[(size_t)(n0 + row) * 2048 + seg + i * 8];
      if (tid < 32) sc[1100 + tid] = bias1[n0 + tid];
    }
    __syncthreads();
    const int mh = wid & 1, kh = wid >> 1;
    const int lrow = lane & 15, lk = (lane >> 4) << 3;
    const int b = mh * 16 + lrow;
    for (int t = 0; t < 64; ++t) {
      wait_ge(c_h1, 32u * (u32)t);   // h1prev ready
      f32x4 ac0 = {0,0,0,0}, ac1 = {0,0,0,0};
      {
        // h1prev slices: kh=0 -> 32..47, kh=1 -> 48..63
        const u16* pb = h1st + (size_t)(t & 1) * 32768 + (size_t)b * 1024 + kh * 512 + lk;
        bf16x8 av[16];
#pragma unroll
        for (int ks = 0; ks < 16; ++ks) issue_lcoh(av[ks], pb + ks * 32);
        vm_wait0();
#pragma unroll
        for (int ks = 0; ks < 16; ++ks) {
          int sl = (32 + kh * 16 + ks) * 32 + lk;
          ac0 = MFMA_BF16(av[ks], *(const bf16x8*)&role[lrow * 2056 + sl], ac0);
          ac1 = MFMA_BF16(av[ks], *(const bf16x8*)&role[(16 + lrow) * 2056 + sl], ac1);
        }
      }
      wait_ge(c_h0, 64u * (u32)(t + 1));
      {
        // h0 slices: kh=0 -> 0..15, kh=1 -> 16..31  (h0(t) in h0st[(t+1)&1])
        const u16* hb = h0st + (size_t)((t + 1) & 1) * 32768 + (size_t)b * 1024 + kh * 512 + lk;
        bf16x8 av[16];
#pragma unroll
        for (int ks = 0; ks < 16; ++ks) issue_lcoh(av[ks], hb + ks * 32);
        vm_wait0();
#pragma unroll
        for (int ks = 0; ks < 16; ++ks) {
          int sl = (kh * 16 + ks) * 32 + lk;
          ac0 = MFMA_BF16(av[ks], *(const bf16x8*)&role[lrow * 2056 + sl], ac0);
          ac1 = MFMA_BF16(av[ks], *(const bf16x8*)&role[(16 + lrow) * 2056 + sl], ac1);
        }
      }
      __syncthreads();
      if (kh == 1) {
        *(f32x4*)&sc[(mh * 64 + lane) * 8]     = ac0;
        *(f32x4*)&sc[(mh * 64 + lane) * 8 + 4] = ac1;
      }
      __syncthreads();
      if (kh == 0) {
        f32x4 o0 = *(const f32x4*)&sc[(mh * 64 + lane) * 8];
        f32x4 o1 = *(const f32x4*)&sc[(mh * 64 + lane) * 8 + 4];
        const int rb = mh * 16 + ((lane >> 4) << 2);
        const int c0g = n0 + lrow, c1g = n0 + 16 + lrow;
        const float bs0 = sc[1100 + lrow], bs1 = sc[1100 + 16 + lrow];
        u16* hn = h1st + (size_t)((t + 1) & 1) * 32768;
#pragma unroll
        for (int j = 0; j < 4; ++j) {
          int row = rb + j;
          u16 v0 = f2bf(tanh_fast(ac0[j] + o0[j] + bs0));
          u16 v1 = f2bf(tanh_fast(ac1[j] + o1[j] + bs1));
          scoh_u16(hn + (size_t)row * 1024 + c0g, v0);
          scoh_u16(hn + (size_t)row * 1024 + c1g, v1);
          h1all[(size_t)(row * 64 + t) * 1024 + c0g] = v0;   // plain (read next kernel)
          h1all[(size_t)(row * 64 + t) * 1024 + c1g] = v1;
        }
      }
      post_add(c_h1);
    }
  }
}

// ---------------------------------------------------------------------------
extern "C" void kernel_launch(void* const* d_in, const int* in_sizes, int n_in,
                              void* d_out, int out_size, void* d_ws, size_t ws_size,
                              hipStream_t stream)
{
  const int*   yin  = (const int*)d_in[0];
  const float* enc  = (const float*)d_in[1];
  const float* dih  = (const float*)d_in[2];
  const int*   msk  = (const int*)d_in[3];
  const float* emb  = (const float*)d_in[4];
  const float* wenc = (const float*)d_in[5];
  const float* wdec = (const float*)d_in[6];
  const float* vw   = (const float*)d_in[7];
  const float* wih0 = (const float*)d_in[8];
  const float* whh0 = (const float*)d_in[9];
  const float* bih0 = (const float*)d_in[10];
  const float* bhh0 = (const float*)d_in[11];
  const float* wih1 = (const float*)d_in[12];
  const float* whh1 = (const float*)d_in[13];
  const float* bih1 = (const float*)d_in[14];
  const float* bhh1 = (const float*)d_in[15];
  const float* fcw  = (const float*)d_in[16];
  const float* fcb  = (const float*)d_in[17];

  char* ws = (char*)d_ws;
  size_t off = 0;
  auto alloc = [&](size_t bytes) {
    char* p = ws + off; off += (bytes + 255) & ~(size_t)255; return p;
  };
  u16*   fcwb    = (u16*)alloc(32768000ULL * 2);
  u16*   encb    = (u16*)alloc(4194304ULL * 2);
  u16*   wencb   = (u16*)alloc(524288ULL * 2);
  u16*   wdecb   = (u16*)alloc(524288ULL * 2);
  u16*   w0cat   = (u16*)alloc(2621440ULL * 2);
  u16*   w1cat   = (u16*)alloc(2097152ULL * 2);
  u16*   embbt   = (u16*)alloc(1048576ULL * 2);
  float* encproj = (float*)alloc(2097152ULL * 4);
  float* decp    = (float*)alloc(16384ULL * 4);
  float* bias0   = (float*)alloc(1024ULL * 4);
  float* bias1   = (float*)alloc(1024ULL * 4);
  u16*   ctxbuf  = (u16*)alloc(2ULL * 32768 * 2);
  u16*   h0st    = (u16*)alloc(2ULL * 32768 * 2);
  u16*   h1st    = (u16*)alloc(2ULL * 32768 * 2);
  u16*   h1all   = (u16*)alloc(2097152ULL * 2);
  float* escb    = (float*)alloc(4096ULL * 4);
  float* psumb   = (float*)alloc(64ULL * 4);
  u32*   cnts    = (u32*)alloc(1024ULL);
  if (off > ws_size) return;  // workspace too small -> visible failure

  float* outlog  = (float*)d_out;                 // [2048][31999]
  float* outattn = outlog + 65533952ULL;          // [32][64][128]

  hipMemsetAsync(cnts, 0, 1024, stream);

  prep_kernel<<<2048, 256, 0, stream>>>(
      fcw, enc, wenc, wdec, wih0, whh0, wih1, whh1,
      bih0, bhh0, bih1, bhh1, emb, yin, dih,
      fcwb, encb, wencb, wdecb, w0cat, w1cat, embbt, bias0, bias1,
      h0st, h1st);

  // enc_proj (prescaled): [4096][512] = encb @ wencb^T
  gemm128<<<32 * 4, 256, 0, stream>>>(encb, wencb, nullptr, encproj,
                                      1024, 512, 512, 4);

  (void)hipFuncSetAttribute((const void*)decoder_persistent,
                            hipFuncAttributeMaxDynamicSharedMemorySize, 141312);
  decoder_persistent<<<240, 256, 141312, stream>>>(
      wdecb, w0cat, w1cat, encb, encproj, embbt, bias0, bias1,
      vw, msk, decp, escb, psumb, ctxbuf, h0st, h1st, h1all, outattn, cnts);

  // logits: [2048][31999] = h1all[2048][1024] @ fcwb[32000][1024]^T + fc_b
  gemm128<<<16 * 250, 256, 0, stream>>>(h1all, fcwb, fcb, outlog,
                                        1024, 31999, 31999, 250);
}